// Round 2
// baseline (705.554 us; speedup 1.0000x reference)
//
#include <hip/hip_runtime.h>
#include <stdint.h>

// ---------------------------------------------------------------------------
// LayerNormDenseGeneral: y = LN(x)*scale+bias; z = y @ W.  Outputs (z, y).
// Shapes: x[S,B,H]=[2048,4,2048] fp32, W[H,F]=[2048,8192] fp32.
// Round 4: GEMM moved to the m201-style quadrant schedule: 256^2 tile, BK=64,
// 8 waves, 4 quadrant-phases per K-tile ({ds_read frags; barrier; setprio;
// 16 MFMA; setprio; barrier}), whole-K-tile staging at tile boundaries with
// a single counted vmcnt(8) (tile t+2 issued while t+1 stays in flight —
// never drained in-loop). LDS swizzle FIXED: slot = chunk ^ (row&7) so 8
// consecutive lanes of a ds_read_b128 hit all 8 bank-quads (round-1's
// (r>>2)&3 variant covered only 4 -> 2.5e7 conflicts).
// LN + transpose kernels byte-identical for counter isolation.
// ws layout: [0, M*K*2) = A bf16 ; [M*K*2, M*K*2 + F*K*2) = Bt bf16. 64 MiB.
// ---------------------------------------------------------------------------

typedef __attribute__((ext_vector_type(8))) short short8;   // 8 x bf16 bits
typedef __attribute__((ext_vector_type(4))) float floatx4;  // MFMA acc

__device__ __forceinline__ unsigned short f2bf(float f) {
    unsigned u = __builtin_bit_cast(unsigned, f);
    u += 0x7fffu + ((u >> 16) & 1u);   // round-to-nearest-even
    return (unsigned short)(u >> 16);
}

// ---------------- LayerNorm: one block per row, H=2048 ---------------------
__global__ __launch_bounds__(256) void ln_kernel(
    const float* __restrict__ x, const float* __restrict__ scale,
    const float* __restrict__ bias, float* __restrict__ y,
    unsigned short* __restrict__ ybf, int H)
{
    const int row = blockIdx.x;
    const float* xr = x + (size_t)row * H;
    const int tid = threadIdx.x;

    // H = 2048: each thread handles float4 at [tid] and [tid+256]
    float4 v0 = ((const float4*)xr)[tid];
    float4 v1 = ((const float4*)xr)[tid + 256];

    float s  = v0.x + v0.y + v0.z + v0.w + v1.x + v1.y + v1.z + v1.w;
    float ss = v0.x*v0.x + v0.y*v0.y + v0.z*v0.z + v0.w*v0.w
             + v1.x*v1.x + v1.y*v1.y + v1.z*v1.z + v1.w*v1.w;

    // wave(64) reduce
    #pragma unroll
    for (int off = 32; off > 0; off >>= 1) {
        s  += __shfl_down(s,  off, 64);
        ss += __shfl_down(ss, off, 64);
    }
    __shared__ float rs[4], rq[4];
    if ((tid & 63) == 0) { rs[tid >> 6] = s; rq[tid >> 6] = ss; }
    __syncthreads();
    float ts = rs[0] + rs[1] + rs[2] + rs[3];
    float tq = rq[0] + rq[1] + rq[2] + rq[3];
    float mean = ts / (float)H;
    float var  = tq / (float)H - mean * mean;
    float rstd = rsqrtf(var + 1e-6f);

    float4 sc0 = ((const float4*)scale)[tid];
    float4 sc1 = ((const float4*)scale)[tid + 256];
    float4 b0  = ((const float4*)bias)[tid];
    float4 b1  = ((const float4*)bias)[tid + 256];

    float4 o0, o1;
    o0.x = (v0.x - mean) * rstd * sc0.x + b0.x;
    o0.y = (v0.y - mean) * rstd * sc0.y + b0.y;
    o0.z = (v0.z - mean) * rstd * sc0.z + b0.z;
    o0.w = (v0.w - mean) * rstd * sc0.w + b0.w;
    o1.x = (v1.x - mean) * rstd * sc1.x + b1.x;
    o1.y = (v1.y - mean) * rstd * sc1.y + b1.y;
    o1.z = (v1.z - mean) * rstd * sc1.z + b1.z;
    o1.w = (v1.w - mean) * rstd * sc1.w + b1.w;

    float* yr = y + (size_t)row * H;
    ((float4*)yr)[tid]       = o0;
    ((float4*)yr)[tid + 256] = o1;

    unsigned short* br = ybf + (size_t)row * H;
    uint2 p0, p1;
    p0.x = (unsigned)f2bf(o0.x) | ((unsigned)f2bf(o0.y) << 16);
    p0.y = (unsigned)f2bf(o0.z) | ((unsigned)f2bf(o0.w) << 16);
    p1.x = (unsigned)f2bf(o1.x) | ((unsigned)f2bf(o1.y) << 16);
    p1.y = (unsigned)f2bf(o1.z) | ((unsigned)f2bf(o1.w) << 16);
    ((uint2*)br)[tid]       = p0;
    ((uint2*)br)[tid + 256] = p1;
}

// -------- transpose-cast: W[K][F] fp32 -> Bt[F][K] bf16, 64x64 tiles -------
__global__ __launch_bounds__(256) void transpose_cast_kernel(
    const float* __restrict__ W, unsigned short* __restrict__ Bt,
    int K, int F)
{
    __shared__ float tile[64][65];
    const int kBase = blockIdx.y * 64;
    const int fBase = blockIdx.x * 64;
    const int tid = threadIdx.x;

    // read: 4 passes x (16 rows of 64 floats), coalesced float4
    #pragma unroll
    for (int p = 0; p < 4; ++p) {
        int kl = (tid >> 4) + p * 16;
        int fl = (tid & 15) * 4;
        float4 v = *(const float4*)&W[(size_t)(kBase + kl) * F + fBase + fl];
        tile[kl][fl]     = v.x;
        tile[kl][fl + 1] = v.y;
        tile[kl][fl + 2] = v.z;
        tile[kl][fl + 3] = v.w;
    }
    __syncthreads();

    // write: 2 passes x (32 f-rows), each thread packs 8 bf16 = 16B store
    #pragma unroll
    for (int p = 0; p < 2; ++p) {
        int fl = (tid >> 3) + p * 32;
        int k8 = (tid & 7) * 8;
        unsigned w[4];
        #pragma unroll
        for (int j = 0; j < 4; ++j) {
            unsigned lo = f2bf(tile[k8 + 2*j][fl]);
            unsigned hi = f2bf(tile[k8 + 2*j + 1][fl]);
            w[j] = lo | (hi << 16);
        }
        uint4 out = make_uint4(w[0], w[1], w[2], w[3]);
        *(uint4*)&Bt[(size_t)(fBase + fl) * K + kBase + k8] = out;
    }
}

// ---------------- GEMM: C[M][N] = A[M][K] * Bt[N][K]^T (bf16 -> fp32) ------
// 256x256 tile, BK=64, 512 threads = 8 waves (2M x 4N), wave tile 128x64.
// LDS 128 KiB = lds[2 buf][32768 shorts]; per buf: A halves at 0/8192,
// B halves at 16384/24576. A-half h = tile rows h*128..h*128+127, each row
// 64 bf16 = 8 chunks of 16B. Swizzle: LDS[r][s] holds global chunk s^(r&7);
// inverse applied to global src of global_load_lds (dest stays linear),
// same XOR on ds_read -> 8 consecutive lanes hit 8 distinct bank-quads.
//
// Per K-tile t (buf p=t&1): 4 quadrant phases (Q00,Q01,Q11,Q10), each
// {ds_read 4-12 frags; s_barrier; setprio(1); 16 MFMA; setprio(0);
// s_barrier}; then stage tile t+2 into buf[p] (WAR guarded by Q10's closing
// barrier), vmcnt(8) retiring tile t+1's 8 loads (t+2's 8 stay in flight),
// s_barrier. vmcnt never reaches 0 in the loop; each tile's loads get a
// full K-tile of compute for latency coverage.
#define GBM 256
#define GBN 256
#define GBK 64

__device__ __forceinline__ void gload16(const unsigned short* src,
                                        unsigned short* dst) {
    __builtin_amdgcn_global_load_lds(
        (const __attribute__((address_space(1))) unsigned int*)src,
        (__attribute__((address_space(3))) unsigned int*)dst, 16, 0, 0);
}

// Stage one full K-tile (A 32KB + B 32KB) = 8 loads/thread.
// o0 = (tid>>3)*K + ((tid&7)^((tid>>3)&7))*8 : inverse-swizzled src offset.
// d0 = tid*8 : linear dest. j walks rows +64 (half/e-slot pairs).
__device__ __forceinline__ void stage_tile(
    const unsigned short* __restrict__ gA,
    const unsigned short* __restrict__ gB,
    unsigned short* dst, int t, int K, int o0, int d0)
{
    const int kb = t * GBK;
    #pragma unroll
    for (int j = 0; j < 4; ++j)
        gload16(gA + (size_t)(o0 + j * 64 * K + kb), dst + j * 4096 + d0);
    #pragma unroll
    for (int j = 0; j < 4; ++j)
        gload16(gB + (size_t)(o0 + j * 64 * K + kb), dst + 16384 + j * 4096 + d0);
}

// One C-quadrant (MH: mi 0-3 vs 4-7, NH: ni 0-1 vs 2-3) x full BK=64.
template<int MH, int NH, bool LA, bool LB>
__device__ __forceinline__ void quad_phase(
    const unsigned short* bufA, const unsigned short* bufB,
    int rowA, int rowB, int s0, int s1,
    short8 (&a)[4][2], short8 (&b)[2][2], floatx4 (&acc)[8][4])
{
    if (LA) {
        #pragma unroll
        for (int i = 0; i < 4; ++i) {
            const unsigned short* rp = bufA + (MH * 64 + i * 16) * 64 + rowA;
            a[i][0] = *(const short8*)(rp + s0);
            a[i][1] = *(const short8*)(rp + s1);
        }
    }
    if (LB) {
        #pragma unroll
        for (int j = 0; j < 2; ++j) {
            const unsigned short* rp = bufB + ((NH * 2 + j) * 16) * 64 + rowB;
            b[j][0] = *(const short8*)(rp + s0);
            b[j][1] = *(const short8*)(rp + s1);
        }
    }
    __builtin_amdgcn_s_barrier();
    __builtin_amdgcn_s_setprio(1);
    #pragma unroll
    for (int i = 0; i < 4; ++i)
        #pragma unroll
        for (int j = 0; j < 2; ++j) {
            acc[MH*4+i][NH*2+j] = __builtin_amdgcn_mfma_f32_16x16x32_bf16(
                a[i][0], b[j][0], acc[MH*4+i][NH*2+j], 0, 0, 0);
            acc[MH*4+i][NH*2+j] = __builtin_amdgcn_mfma_f32_16x16x32_bf16(
                a[i][1], b[j][1], acc[MH*4+i][NH*2+j], 0, 0, 0);
        }
    __builtin_amdgcn_s_setprio(0);
    __builtin_amdgcn_s_barrier();
}

__global__ __launch_bounds__(512, 2) void gemm_bf16_8w(
    const unsigned short* __restrict__ A,   // [M][K] bf16
    const unsigned short* __restrict__ Bt,  // [N][K] bf16
    float* __restrict__ C,                  // [M][N] fp32
    int M, int N, int K)
{
    __shared__ __align__(128) unsigned short lds[2][32768]; // 128 KiB

    const int tid   = threadIdx.x;
    const int lane  = tid & 63;
    const int wave  = tid >> 6;     // 0..7
    const int waveM = wave >> 2;    // 0..1
    const int waveN = wave & 3;     // 0..3
    const int quad  = lane >> 4;    // 0..3
    const int l16   = lane & 15;
    const int xs    = l16 & 7;              // row&7 for all fragment rows
    const int s0    = (quad ^ xs) * 8;      // slot offset (shorts), ks=0
    const int s1    = ((4 | quad) ^ xs) * 8;// slot offset, ks=1
    const int rowA  = l16 * 64;
    const int rowB  = ((waveN & 1) * 64 + l16) * 64;

    const int r0 = tid >> 3;                       // staging row in half
    const int g0 = (tid & 7) ^ (r0 & 7);           // inverse-swizzled chunk
    const int o0 = r0 * K + g0 * 8;                // src offset (shorts)
    const int d0 = tid * 8;                        // linear dest (shorts)

    // XCD-aware bijective swizzle (nwg = 1024, divisible by 8)
    const int nwg = gridDim.x;
    const int cpx = nwg >> 3;
    const int bid = blockIdx.x;
    const int wg  = (bid & 7) * cpx + (bid >> 3);
    const int tilesN = N >> 8;
    const int tm = wg / tilesN;
    const int tn = wg % tilesN;

    const unsigned short* gA = A  + (size_t)tm * GBM * K;
    const unsigned short* gB = Bt + (size_t)tn * GBN * K;

    const int NT = K >> 6;          // K-tiles of 64 (=32 here, even)

    floatx4 acc[8][4] = {};
    short8 a[4][2], b[2][2];

    unsigned short* bufA0 = &lds[0][0] + waveM * 8192;           // my A-half
    unsigned short* bufB0 = &lds[0][0] + 16384 + (waveN >> 1) * 8192;

    // prologue: tile0 -> buf0, tile1 -> buf1; retire tile0, keep tile1 in
    // flight across the first barrier.
    stage_tile(gA, gB, &lds[0][0], 0, K, o0, d0);
    stage_tile(gA, gB, &lds[1][0], 1, K, o0, d0);
    asm volatile("s_waitcnt vmcnt(8)" ::: "memory");
    __builtin_amdgcn_s_barrier();

    for (int t = 0; t < NT; t += 2) {
        // ---- K-tile t (buf 0) ----
        quad_phase<0,0,true ,true >(bufA0, bufB0, rowA, rowB, s0, s1, a, b, acc);
        quad_phase<0,1,false,true >(bufA0, bufB0, rowA, rowB, s0, s1, a, b, acc);
        quad_phase<1,1,true ,false>(bufA0, bufB0, rowA, rowB, s0, s1, a, b, acc);
        quad_phase<1,0,false,true >(bufA0, bufB0, rowA, rowB, s0, s1, a, b, acc);
        {
            int ts = (t + 2 < NT) ? (t + 2) : (NT - 1);   // clamp: dup never read
            stage_tile(gA, gB, &lds[0][0], ts, K, o0, d0);
            asm volatile("s_waitcnt vmcnt(8)" ::: "memory"); // retire tile t+1
            __builtin_amdgcn_s_barrier();
        }
        // ---- K-tile t+1 (buf 1) ----
        quad_phase<0,0,true ,true >(bufA0 + 32768, bufB0 + 32768, rowA, rowB, s0, s1, a, b, acc);
        quad_phase<0,1,false,true >(bufA0 + 32768, bufB0 + 32768, rowA, rowB, s0, s1, a, b, acc);
        quad_phase<1,1,true ,false>(bufA0 + 32768, bufB0 + 32768, rowA, rowB, s0, s1, a, b, acc);
        quad_phase<1,0,false,true >(bufA0 + 32768, bufB0 + 32768, rowA, rowB, s0, s1, a, b, acc);
        {
            int ts = (t + 3 < NT) ? (t + 3) : (NT - 1);
            stage_tile(gA, gB, &lds[1][0], ts, K, o0, d0);
            asm volatile("s_waitcnt vmcnt(8)" ::: "memory"); // retire tile t+2
            __builtin_amdgcn_s_barrier();
        }
    }

    // epilogue: C/D layout col = lane&15 (N from B), row = quad*4 + reg (M)
    const size_t bm = (size_t)tm * GBM;
    const size_t bn = (size_t)tn * GBN;
    #pragma unroll
    for (int mi = 0; mi < 8; ++mi) {
        #pragma unroll
        for (int ni = 0; ni < 4; ++ni) {
            size_t col = bn + (size_t)waveN * 64 + ni * 16 + l16;
            #pragma unroll
            for (int r = 0; r < 4; ++r) {
                size_t row = bm + (size_t)waveM * 128 + mi * 16 + quad * 4 + r;
                C[row * N + col] = acc[mi][ni][r];
            }
        }
    }
}

// ---------------------------------------------------------------------------
extern "C" void kernel_launch(void* const* d_in, const int* in_sizes, int n_in,
                              void* d_out, int out_size, void* d_ws, size_t ws_size,
                              hipStream_t stream) {
    const float* x      = (const float*)d_in[0];
    const float* scale  = (const float*)d_in[1];
    const float* lnbias = (const float*)d_in[2];
    const float* W      = (const float*)d_in[3];

    const int H = in_sizes[1];                 // 2048
    const int M = in_sizes[0] / H;             // S*B = 8192
    const int F = in_sizes[3] / H;             // 8192

    float* z = (float*)d_out;                  // [M][F]
    float* y = z + (size_t)M * F;              // [M][H]

    unsigned short* Abf = (unsigned short*)d_ws;            // [M][H] bf16
    unsigned short* Btb = Abf + (size_t)M * H;              // [F][H] bf16

    ln_kernel<<<M, 256, 0, stream>>>(x, scale, lnbias, y, Abf, H);
    transpose_cast_kernel<<<dim3(F / 64, H / 64), 256, 0, stream>>>(W, Btb, H, F);
    gemm_bf16_8w<<<dim3((M / GBM) * (F / GBN)), 512, 0, stream>>>(Abf, Btb, z, M, F, H);
}

// Round 3
// 689.721 us; speedup vs baseline: 1.0230x; 1.0230x over previous
//
#include <hip/hip_runtime.h>
#include <stdint.h>

// ---------------------------------------------------------------------------
// LayerNormDenseGeneral: y = LN(x)*scale+bias; z = y @ W.  Outputs (z, y).
// Shapes: x[S,B,H]=[2048,4,2048] fp32, W[H,F]=[2048,8192] fp32.
// Round 5: GEMM restructured to the fine-grained interleaved schedule
// (m196's isolated lever): BK=32, 4-buffer LDS ring (4x32KiB), 2 phases per
// K-tile, ONE operand stage embedded per phase, prefetch distance 3 K-tiles,
// counted vmcnt(8) once per K-tile after the MFMA cluster (never drains
// in-loop). B-fragments live in registers across both phases (12 ds_reads /
// K-tile / wave, minimal). Swizzle: phys slot = chunk ^ ((row>>1)&3) ->
// 8 consecutive lanes hit bank-quads {0,4,1,5,2,6,3,7} (verified by hand).
// LN + transpose kernels byte-identical for counter isolation.
// ws layout: [0, M*K*2) = A bf16 ; [M*K*2, M*K*2 + F*K*2) = Bt bf16. 64 MiB.
// ---------------------------------------------------------------------------

typedef __attribute__((ext_vector_type(8))) short short8;   // 8 x bf16 bits
typedef __attribute__((ext_vector_type(4))) float floatx4;  // MFMA acc

__device__ __forceinline__ unsigned short f2bf(float f) {
    unsigned u = __builtin_bit_cast(unsigned, f);
    u += 0x7fffu + ((u >> 16) & 1u);   // round-to-nearest-even
    return (unsigned short)(u >> 16);
}

// ---------------- LayerNorm: one block per row, H=2048 ---------------------
__global__ __launch_bounds__(256) void ln_kernel(
    const float* __restrict__ x, const float* __restrict__ scale,
    const float* __restrict__ bias, float* __restrict__ y,
    unsigned short* __restrict__ ybf, int H)
{
    const int row = blockIdx.x;
    const float* xr = x + (size_t)row * H;
    const int tid = threadIdx.x;

    // H = 2048: each thread handles float4 at [tid] and [tid+256]
    float4 v0 = ((const float4*)xr)[tid];
    float4 v1 = ((const float4*)xr)[tid + 256];

    float s  = v0.x + v0.y + v0.z + v0.w + v1.x + v1.y + v1.z + v1.w;
    float ss = v0.x*v0.x + v0.y*v0.y + v0.z*v0.z + v0.w*v0.w
             + v1.x*v1.x + v1.y*v1.y + v1.z*v1.z + v1.w*v1.w;

    // wave(64) reduce
    #pragma unroll
    for (int off = 32; off > 0; off >>= 1) {
        s  += __shfl_down(s,  off, 64);
        ss += __shfl_down(ss, off, 64);
    }
    __shared__ float rs[4], rq[4];
    if ((tid & 63) == 0) { rs[tid >> 6] = s; rq[tid >> 6] = ss; }
    __syncthreads();
    float ts = rs[0] + rs[1] + rs[2] + rs[3];
    float tq = rq[0] + rq[1] + rq[2] + rq[3];
    float mean = ts / (float)H;
    float var  = tq / (float)H - mean * mean;
    float rstd = rsqrtf(var + 1e-6f);

    float4 sc0 = ((const float4*)scale)[tid];
    float4 sc1 = ((const float4*)scale)[tid + 256];
    float4 b0  = ((const float4*)bias)[tid];
    float4 b1  = ((const float4*)bias)[tid + 256];

    float4 o0, o1;
    o0.x = (v0.x - mean) * rstd * sc0.x + b0.x;
    o0.y = (v0.y - mean) * rstd * sc0.y + b0.y;
    o0.z = (v0.z - mean) * rstd * sc0.z + b0.z;
    o0.w = (v0.w - mean) * rstd * sc0.w + b0.w;
    o1.x = (v1.x - mean) * rstd * sc1.x + b1.x;
    o1.y = (v1.y - mean) * rstd * sc1.y + b1.y;
    o1.z = (v1.z - mean) * rstd * sc1.z + b1.z;
    o1.w = (v1.w - mean) * rstd * sc1.w + b1.w;

    float* yr = y + (size_t)row * H;
    ((float4*)yr)[tid]       = o0;
    ((float4*)yr)[tid + 256] = o1;

    unsigned short* br = ybf + (size_t)row * H;
    uint2 p0, p1;
    p0.x = (unsigned)f2bf(o0.x) | ((unsigned)f2bf(o0.y) << 16);
    p0.y = (unsigned)f2bf(o0.z) | ((unsigned)f2bf(o0.w) << 16);
    p1.x = (unsigned)f2bf(o1.x) | ((unsigned)f2bf(o1.y) << 16);
    p1.y = (unsigned)f2bf(o1.z) | ((unsigned)f2bf(o1.w) << 16);
    ((uint2*)br)[tid]       = p0;
    ((uint2*)br)[tid + 256] = p1;
}

// -------- transpose-cast: W[K][F] fp32 -> Bt[F][K] bf16, 64x64 tiles -------
__global__ __launch_bounds__(256) void transpose_cast_kernel(
    const float* __restrict__ W, unsigned short* __restrict__ Bt,
    int K, int F)
{
    __shared__ float tile[64][65];
    const int kBase = blockIdx.y * 64;
    const int fBase = blockIdx.x * 64;
    const int tid = threadIdx.x;

    // read: 4 passes x (16 rows of 64 floats), coalesced float4
    #pragma unroll
    for (int p = 0; p < 4; ++p) {
        int kl = (tid >> 4) + p * 16;
        int fl = (tid & 15) * 4;
        float4 v = *(const float4*)&W[(size_t)(kBase + kl) * F + fBase + fl];
        tile[kl][fl]     = v.x;
        tile[kl][fl + 1] = v.y;
        tile[kl][fl + 2] = v.z;
        tile[kl][fl + 3] = v.w;
    }
    __syncthreads();

    // write: 2 passes x (32 f-rows), each thread packs 8 bf16 = 16B store
    #pragma unroll
    for (int p = 0; p < 2; ++p) {
        int fl = (tid >> 3) + p * 32;
        int k8 = (tid & 7) * 8;
        unsigned w[4];
        #pragma unroll
        for (int j = 0; j < 4; ++j) {
            unsigned lo = f2bf(tile[k8 + 2*j][fl]);
            unsigned hi = f2bf(tile[k8 + 2*j + 1][fl]);
            w[j] = lo | (hi << 16);
        }
        uint4 out = make_uint4(w[0], w[1], w[2], w[3]);
        *(uint4*)&Bt[(size_t)(fBase + fl) * K + kBase + k8] = out;
    }
}

// ---------------- GEMM: C[M][N] = A[M][K] * Bt[N][K]^T (bf16 -> fp32) ------
// 256x256 tile, BK=32, 512 threads = 8 waves (2M x 4N), wave tile 128x64.
// LDS ring: 4 bufs x (A[256][32] @ 0 + B[256][32] @ 8192 shorts) = 128 KiB.
// Row = 64B = 4 chunks of 16B; phys slot s of row r holds logical chunk
// s ^ ((r>>1)&3). ds_read_b128 fragment reads: lanes l16=0..7 hit bank-quads
// {0,4,1,5,2,6,3,7} -> conflict-free. gload_lds dest stays linear; inverse
// XOR applied to the per-lane global source address.
//
// Per K-tile t (buf t&3), 2 phases:
//  ph0: ds_read a[0..3](rows 0-63 of wave half) + b[0..3]; stage A(t+3);
//       barrier; lgkmcnt(0); setprio(1); 16 MFMA (mi 0-3); setprio(0); barrier
//  ph1: ds_read a[0..3](rows 64-127); b reused from regs; stage B(t+3);
//       barrier; lgkmcnt(0); setprio(1); 16 MFMA (mi 4-7); setprio(0);
//       vmcnt(8); barrier
// vmcnt(8) retires {A,B}(t+1) (read after this barrier) while {A,B}(t+2),
// {A,B}(t+3) (8 loads) stay in flight -> never drains; each stage has ~4
// phases of compute to cover HBM latency. Tail stages dup tile NT-1 into a
// dead buffer to keep the wait-count ledger uniform.
#define GBM 256
#define GBN 256
#define GBK 32

__device__ __forceinline__ void gload16(const unsigned short* src,
                                        unsigned short* dst) {
    __builtin_amdgcn_global_load_lds(
        (const __attribute__((address_space(1))) unsigned int*)src,
        (__attribute__((address_space(3))) unsigned int*)dst, 16, 0, 0);
}

// stage one operand K-tile (256 rows x 32 k = 16KB) = 2 loads/thread
__device__ __forceinline__ void stage_op(
    const unsigned short* __restrict__ g, unsigned short* dst,
    int t, int K, int tid)
{
    #pragma unroll
    for (int i = 0; i < 2; ++i) {
        int e = i * 512 + tid;
        int r = e >> 2;                         // row 0..255
        int c = (e & 3) ^ ((r >> 1) & 3);       // inverse swizzle on source
        gload16(g + (size_t)r * K + t * GBK + c * 8, dst + e * 8);
    }
}

__global__ __launch_bounds__(512, 2) void gemm_bf16_8w(
    const unsigned short* __restrict__ A,   // [M][K] bf16
    const unsigned short* __restrict__ Bt,  // [N][K] bf16
    float* __restrict__ C,                  // [M][N] fp32
    int M, int N, int K)
{
    __shared__ __align__(128) unsigned short lds[4][16384]; // 128 KiB ring

    const int tid   = threadIdx.x;
    const int lane  = tid & 63;
    const int wave  = tid >> 6;     // 0..7
    const int waveM = wave >> 2;    // 0..1
    const int waveN = wave & 3;     // 0..3
    const int quad  = lane >> 4;    // 0..3 (k-chunk)
    const int l16   = lane & 15;
    // fragment rows are (multiple of 8) + l16, so (r>>1)&3 == (l16>>1)&3:
    const int soff  = (quad ^ ((l16 >> 1) & 3)) * 8;  // swizzled slot (shorts)
    const int rowA0 = waveM * 128 + l16;
    const int rowB0 = waveN * 64 + l16;

    // XCD-aware bijective swizzle (nwg = 1024, divisible by 8)
    const int nwg = gridDim.x;
    const int cpx = nwg >> 3;
    const int bid = blockIdx.x;
    const int wg  = (bid & 7) * cpx + (bid >> 3);
    const int tilesN = N >> 8;
    const int tm = wg / tilesN;
    const int tn = wg % tilesN;

    const unsigned short* gA = A  + (size_t)tm * GBM * K;
    const unsigned short* gB = Bt + (size_t)tn * GBN * K;

    const int NT = K >> 5;          // K-tiles of 32 (= 64 here, mult of 4)

    floatx4 acc[8][4] = {};

    // prologue: stage tiles 0,1,2 (12 loads); retire tile0 (keep 8 in flight)
    stage_op(gA, &lds[0][0],    0, K, tid);
    stage_op(gB, &lds[0][8192], 0, K, tid);
    stage_op(gA, &lds[1][0],    1, K, tid);
    stage_op(gB, &lds[1][8192], 1, K, tid);
    stage_op(gA, &lds[2][0],    2, K, tid);
    stage_op(gB, &lds[2][8192], 2, K, tid);
    asm volatile("s_waitcnt vmcnt(8)" ::: "memory");
    __builtin_amdgcn_s_barrier();

    for (int t = 0; t < NT; t += 4) {
        #pragma unroll
        for (int u = 0; u < 4; ++u) {
            const int tt = t + u;
            const unsigned short* bufA = &lds[u][0];
            const unsigned short* bufB = &lds[u][8192];
            unsigned short* pre = &lds[(u + 3) & 3][0];
            int ts = tt + 3; if (ts > NT - 1) ts = NT - 1;  // tail: dup, dead buf

            short8 a[4], b[4];
            // ---------------- phase 0 (mi 0-3) ----------------
            #pragma unroll
            for (int i = 0; i < 4; ++i)
                a[i] = *(const short8*)(bufA + (rowA0 + i * 16) * 32 + soff);
            #pragma unroll
            for (int j = 0; j < 4; ++j)
                b[j] = *(const short8*)(bufB + (rowB0 + j * 16) * 32 + soff);
            stage_op(gA, pre, ts, K, tid);
            __builtin_amdgcn_sched_barrier(0);
            __builtin_amdgcn_s_barrier();
            asm volatile("s_waitcnt lgkmcnt(0)" ::: "memory");
            __builtin_amdgcn_sched_barrier(0);
            __builtin_amdgcn_s_setprio(1);
            #pragma unroll
            for (int i = 0; i < 4; ++i)
                #pragma unroll
                for (int j = 0; j < 4; ++j)
                    acc[i][j] = __builtin_amdgcn_mfma_f32_16x16x32_bf16(
                        a[i], b[j], acc[i][j], 0, 0, 0);
            __builtin_amdgcn_s_setprio(0);
            __builtin_amdgcn_s_barrier();

            // ---------------- phase 1 (mi 4-7), b reused ----------------
            #pragma unroll
            for (int i = 0; i < 4; ++i)
                a[i] = *(const short8*)(bufA + (rowA0 + 64 + i * 16) * 32 + soff);
            stage_op(gB, pre + 8192, ts, K, tid);
            __builtin_amdgcn_sched_barrier(0);
            __builtin_amdgcn_s_barrier();
            asm volatile("s_waitcnt lgkmcnt(0)" ::: "memory");
            __builtin_amdgcn_sched_barrier(0);
            __builtin_amdgcn_s_setprio(1);
            #pragma unroll
            for (int i = 0; i < 4; ++i)
                #pragma unroll
                for (int j = 0; j < 4; ++j)
                    acc[4 + i][j] = __builtin_amdgcn_mfma_f32_16x16x32_bf16(
                        a[i], b[j], acc[4 + i][j], 0, 0, 0);
            __builtin_amdgcn_s_setprio(0);
            // retire {A,B}(tt+1) (read after next barrier); keep 8 in flight
            asm volatile("s_waitcnt vmcnt(8)" ::: "memory");
            __builtin_amdgcn_s_barrier();
        }
    }

    // epilogue: C/D layout col = lane&15 (N from B), row = quad*4 + reg (M)
    const size_t bm = (size_t)tm * GBM;
    const size_t bn = (size_t)tn * GBN;
    #pragma unroll
    for (int mi = 0; mi < 8; ++mi) {
        #pragma unroll
        for (int ni = 0; ni < 4; ++ni) {
            size_t col = bn + (size_t)waveN * 64 + ni * 16 + l16;
            #pragma unroll
            for (int r = 0; r < 4; ++r) {
                size_t row = bm + (size_t)waveM * 128 + mi * 16 + quad * 4 + r;
                C[row * N + col] = acc[mi][ni][r];
            }
        }
    }
}

// ---------------------------------------------------------------------------
extern "C" void kernel_launch(void* const* d_in, const int* in_sizes, int n_in,
                              void* d_out, int out_size, void* d_ws, size_t ws_size,
                              hipStream_t stream) {
    const float* x      = (const float*)d_in[0];
    const float* scale  = (const float*)d_in[1];
    const float* lnbias = (const float*)d_in[2];
    const float* W      = (const float*)d_in[3];

    const int H = in_sizes[1];                 // 2048
    const int M = in_sizes[0] / H;             // S*B = 8192
    const int F = in_sizes[3] / H;             // 8192

    float* z = (float*)d_out;                  // [M][F]
    float* y = z + (size_t)M * F;              // [M][H]

    unsigned short* Abf = (unsigned short*)d_ws;            // [M][H] bf16
    unsigned short* Btb = Abf + (size_t)M * H;              // [F][H] bf16

    ln_kernel<<<M, 256, 0, stream>>>(x, scale, lnbias, y, Abf, H);
    transpose_cast_kernel<<<dim3(F / 64, H / 64), 256, 0, stream>>>(W, Btb, H, F);
    gemm_bf16_8w<<<dim3((M / GBM) * (F / GBN)), 512, 0, stream>>>(Abf, Btb, z, M, F, H);
}

// Round 4
// 682.126 us; speedup vs baseline: 1.0343x; 1.0111x over previous
//
#include <hip/hip_runtime.h>
#include <stdint.h>

// ---------------------------------------------------------------------------
// LayerNormDenseGeneral: y = LN(x)*scale+bias; z = y @ W.  Outputs (z, y).
// Shapes: x[S,B,H]=[2048,4,2048] fp32, W[H,F]=[2048,8192] fp32.
// Round 6: GEMM de-lockstepped. Cycle model of round 5 (2840 cyc/K-tile/CU =
// MFMA 1030 + LDS 1000 + ~800 barrier overhead) showed the per-phase double
// barriers force all 8 waves into the same section -> LDS and MFMA pipes ADD
// instead of overlapping. Hazard audit: only ONE barrier per K-tile is
// needed ({vmcnt(8) lgkmcnt(0); s_barrier} -- RAW for tile t+1 established
// block-wide, WAR: stages only touch buf[u-1] which nobody reads in tile t).
// Waves now free-run within a tile: 4 prefetch loads -> 12 ds_read_b128 ->
// 32 MFMA (setprio-wrapped; wave role diversity now exists for it to
// arbitrate). Barrier count 256 -> 64. Swizzle/ledger unchanged from r5
// (conflicts = 0, 8 loads in flight across every barrier, never drains).
// LN + transpose kernels byte-identical for counter isolation.
// ws layout: [0, M*K*2) = A bf16 ; [M*K*2, M*K*2 + F*K*2) = Bt bf16. 64 MiB.
// ---------------------------------------------------------------------------

typedef __attribute__((ext_vector_type(8))) short short8;   // 8 x bf16 bits
typedef __attribute__((ext_vector_type(4))) float floatx4;  // MFMA acc

__device__ __forceinline__ unsigned short f2bf(float f) {
    unsigned u = __builtin_bit_cast(unsigned, f);
    u += 0x7fffu + ((u >> 16) & 1u);   // round-to-nearest-even
    return (unsigned short)(u >> 16);
}

// ---------------- LayerNorm: one block per row, H=2048 ---------------------
__global__ __launch_bounds__(256) void ln_kernel(
    const float* __restrict__ x, const float* __restrict__ scale,
    const float* __restrict__ bias, float* __restrict__ y,
    unsigned short* __restrict__ ybf, int H)
{
    const int row = blockIdx.x;
    const float* xr = x + (size_t)row * H;
    const int tid = threadIdx.x;

    // H = 2048: each thread handles float4 at [tid] and [tid+256]
    float4 v0 = ((const float4*)xr)[tid];
    float4 v1 = ((const float4*)xr)[tid + 256];

    float s  = v0.x + v0.y + v0.z + v0.w + v1.x + v1.y + v1.z + v1.w;
    float ss = v0.x*v0.x + v0.y*v0.y + v0.z*v0.z + v0.w*v0.w
             + v1.x*v1.x + v1.y*v1.y + v1.z*v1.z + v1.w*v1.w;

    // wave(64) reduce
    #pragma unroll
    for (int off = 32; off > 0; off >>= 1) {
        s  += __shfl_down(s,  off, 64);
        ss += __shfl_down(ss, off, 64);
    }
    __shared__ float rs[4], rq[4];
    if ((tid & 63) == 0) { rs[tid >> 6] = s; rq[tid >> 6] = ss; }
    __syncthreads();
    float ts = rs[0] + rs[1] + rs[2] + rs[3];
    float tq = rq[0] + rq[1] + rq[2] + rq[3];
    float mean = ts / (float)H;
    float var  = tq / (float)H - mean * mean;
    float rstd = rsqrtf(var + 1e-6f);

    float4 sc0 = ((const float4*)scale)[tid];
    float4 sc1 = ((const float4*)scale)[tid + 256];
    float4 b0  = ((const float4*)bias)[tid];
    float4 b1  = ((const float4*)bias)[tid + 256];

    float4 o0, o1;
    o0.x = (v0.x - mean) * rstd * sc0.x + b0.x;
    o0.y = (v0.y - mean) * rstd * sc0.y + b0.y;
    o0.z = (v0.z - mean) * rstd * sc0.z + b0.z;
    o0.w = (v0.w - mean) * rstd * sc0.w + b0.w;
    o1.x = (v1.x - mean) * rstd * sc1.x + b1.x;
    o1.y = (v1.y - mean) * rstd * sc1.y + b1.y;
    o1.z = (v1.z - mean) * rstd * sc1.z + b1.z;
    o1.w = (v1.w - mean) * rstd * sc1.w + b1.w;

    float* yr = y + (size_t)row * H;
    ((float4*)yr)[tid]       = o0;
    ((float4*)yr)[tid + 256] = o1;

    unsigned short* br = ybf + (size_t)row * H;
    uint2 p0, p1;
    p0.x = (unsigned)f2bf(o0.x) | ((unsigned)f2bf(o0.y) << 16);
    p0.y = (unsigned)f2bf(o0.z) | ((unsigned)f2bf(o0.w) << 16);
    p1.x = (unsigned)f2bf(o1.x) | ((unsigned)f2bf(o1.y) << 16);
    p1.y = (unsigned)f2bf(o1.z) | ((unsigned)f2bf(o1.w) << 16);
    ((uint2*)br)[tid]       = p0;
    ((uint2*)br)[tid + 256] = p1;
}

// -------- transpose-cast: W[K][F] fp32 -> Bt[F][K] bf16, 64x64 tiles -------
__global__ __launch_bounds__(256) void transpose_cast_kernel(
    const float* __restrict__ W, unsigned short* __restrict__ Bt,
    int K, int F)
{
    __shared__ float tile[64][65];
    const int kBase = blockIdx.y * 64;
    const int fBase = blockIdx.x * 64;
    const int tid = threadIdx.x;

    // read: 4 passes x (16 rows of 64 floats), coalesced float4
    #pragma unroll
    for (int p = 0; p < 4; ++p) {
        int kl = (tid >> 4) + p * 16;
        int fl = (tid & 15) * 4;
        float4 v = *(const float4*)&W[(size_t)(kBase + kl) * F + fBase + fl];
        tile[kl][fl]     = v.x;
        tile[kl][fl + 1] = v.y;
        tile[kl][fl + 2] = v.z;
        tile[kl][fl + 3] = v.w;
    }
    __syncthreads();

    // write: 2 passes x (32 f-rows), each thread packs 8 bf16 = 16B store
    #pragma unroll
    for (int p = 0; p < 2; ++p) {
        int fl = (tid >> 3) + p * 32;
        int k8 = (tid & 7) * 8;
        unsigned w[4];
        #pragma unroll
        for (int j = 0; j < 4; ++j) {
            unsigned lo = f2bf(tile[k8 + 2*j][fl]);
            unsigned hi = f2bf(tile[k8 + 2*j + 1][fl]);
            w[j] = lo | (hi << 16);
        }
        uint4 out = make_uint4(w[0], w[1], w[2], w[3]);
        *(uint4*)&Bt[(size_t)(fBase + fl) * K + kBase + k8] = out;
    }
}

// ---------------- GEMM: C[M][N] = A[M][K] * Bt[N][K]^T (bf16 -> fp32) ------
// 256x256 tile, BK=32, 512 threads = 8 waves (2M x 4N), wave tile 128x64.
// LDS ring: 4 bufs x (A[256][32] @ 0 + B[256][32] @ 8192 shorts) = 128 KiB.
// Row = 64B = 4 chunks of 16B; phys slot s of row r holds logical chunk
// s ^ ((r>>1)&3). ds_read_b128 fragment reads: lanes l16=0..7 hit bank-quads
// {0,4,1,5,2,6,3,7} -> conflict-free. gload_lds dest stays linear; inverse
// XOR applied to the per-lane global source address.
//
// Per K-tile t (buf u=t&3), free-run body (NO intra-tile barriers):
//   issue 4 prefetch gload_lds for tile t+3 -> buf[u-1 mod 4]
//   12 ds_read_b128 (a rows 0-63, 64-127 of wave half; b rows)
//   setprio(1); 32 MFMA; setprio(0)
//   s_waitcnt vmcnt(8) lgkmcnt(0); s_barrier      <- ONE barrier per tile
// vmcnt(8) retires tile t+1's 4 loads (read after this barrier) while tiles
// t+2, t+3 (8 loads) stay in flight -> never drains. lgkmcnt(0) guarantees
// this wave's LDS reads of buf[u] are complete before tile t+1's stages
// (which overwrite buf[u]) can be issued by any wave past the barrier.
#define GBM 256
#define GBN 256
#define GBK 32

__device__ __forceinline__ void gload16(const unsigned short* src,
                                        unsigned short* dst) {
    __builtin_amdgcn_global_load_lds(
        (const __attribute__((address_space(1))) unsigned int*)src,
        (__attribute__((address_space(3))) unsigned int*)dst, 16, 0, 0);
}

// stage one operand K-tile (256 rows x 32 k = 16KB) = 2 loads/thread
__device__ __forceinline__ void stage_op(
    const unsigned short* __restrict__ g, unsigned short* dst,
    int t, int K, int tid)
{
    #pragma unroll
    for (int i = 0; i < 2; ++i) {
        int e = i * 512 + tid;
        int r = e >> 2;                         // row 0..255
        int c = (e & 3) ^ ((r >> 1) & 3);       // inverse swizzle on source
        gload16(g + (size_t)r * K + t * GBK + c * 8, dst + e * 8);
    }
}

__global__ __launch_bounds__(512, 2) void gemm_bf16_8w(
    const unsigned short* __restrict__ A,   // [M][K] bf16
    const unsigned short* __restrict__ Bt,  // [N][K] bf16
    float* __restrict__ C,                  // [M][N] fp32
    int M, int N, int K)
{
    __shared__ __align__(128) unsigned short lds[4][16384]; // 128 KiB ring

    const int tid   = threadIdx.x;
    const int lane  = tid & 63;
    const int wave  = tid >> 6;     // 0..7
    const int waveM = wave >> 2;    // 0..1
    const int waveN = wave & 3;     // 0..3
    const int quad  = lane >> 4;    // 0..3 (k-chunk)
    const int l16   = lane & 15;
    // fragment rows are (multiple of 8) + l16, so (r>>1)&3 == (l16>>1)&3:
    const int soff  = (quad ^ ((l16 >> 1) & 3)) * 8;  // swizzled slot (shorts)
    const int rowA0 = waveM * 128 + l16;
    const int rowB0 = waveN * 64 + l16;

    // XCD-aware bijective swizzle (nwg = 1024, divisible by 8)
    const int nwg = gridDim.x;
    const int cpx = nwg >> 3;
    const int bid = blockIdx.x;
    const int wg  = (bid & 7) * cpx + (bid >> 3);
    const int tilesN = N >> 8;
    const int tm = wg / tilesN;
    const int tn = wg % tilesN;

    const unsigned short* gA = A  + (size_t)tm * GBM * K;
    const unsigned short* gB = Bt + (size_t)tn * GBN * K;

    const int NT = K >> 5;          // K-tiles of 32 (= 64 here, mult of 4)

    floatx4 acc[8][4] = {};

    // prologue: stage tiles 0,1,2 (12 loads); retire tile0 (keep 8 in flight)
    stage_op(gA, &lds[0][0],    0, K, tid);
    stage_op(gB, &lds[0][8192], 0, K, tid);
    stage_op(gA, &lds[1][0],    1, K, tid);
    stage_op(gB, &lds[1][8192], 1, K, tid);
    stage_op(gA, &lds[2][0],    2, K, tid);
    stage_op(gB, &lds[2][8192], 2, K, tid);
    asm volatile("s_waitcnt vmcnt(8)" ::: "memory");
    __builtin_amdgcn_s_barrier();

    for (int t = 0; t < NT; t += 4) {
        #pragma unroll
        for (int u = 0; u < 4; ++u) {
            const int tt = t + u;
            const unsigned short* bufA = &lds[u][0];
            const unsigned short* bufB = &lds[u][8192];
            unsigned short* pre = &lds[(u + 3) & 3][0];
            int ts = tt + 3; if (ts > NT - 1) ts = NT - 1;  // tail: dup, dead buf

            // prefetch tile tt+3 (4 loads; ~3 K-tiles of compute as cover)
            stage_op(gA, pre, ts, K, tid);
            stage_op(gB, pre + 8192, ts, K, tid);

            // all 12 fragment reads of tile tt; compiler inserts fine-grained
            // lgkmcnt before dependent MFMAs and software-pipelines freely
            short8 a0[4], a1[4], b[4];
            #pragma unroll
            for (int i = 0; i < 4; ++i)
                a0[i] = *(const short8*)(bufA + (rowA0 + i * 16) * 32 + soff);
            #pragma unroll
            for (int j = 0; j < 4; ++j)
                b[j] = *(const short8*)(bufB + (rowB0 + j * 16) * 32 + soff);
            #pragma unroll
            for (int i = 0; i < 4; ++i)
                a1[i] = *(const short8*)(bufA + (rowA0 + 64 + i * 16) * 32 + soff);

            __builtin_amdgcn_s_setprio(1);
            #pragma unroll
            for (int i = 0; i < 4; ++i)
                #pragma unroll
                for (int j = 0; j < 4; ++j)
                    acc[i][j] = __builtin_amdgcn_mfma_f32_16x16x32_bf16(
                        a0[i], b[j], acc[i][j], 0, 0, 0);
            #pragma unroll
            for (int i = 0; i < 4; ++i)
                #pragma unroll
                for (int j = 0; j < 4; ++j)
                    acc[4 + i][j] = __builtin_amdgcn_mfma_f32_16x16x32_bf16(
                        a1[i], b[j], acc[4 + i][j], 0, 0, 0);
            __builtin_amdgcn_s_setprio(0);

            // ONE barrier per K-tile: retire tile tt+1's loads (8 stay in
            // flight); drain my LDS reads so tile tt+1's stages can't
            // overwrite buf[u] under them.
            asm volatile("s_waitcnt vmcnt(8) lgkmcnt(0)" ::: "memory");
            __builtin_amdgcn_s_barrier();
        }
    }

    // epilogue: C/D layout col = lane&15 (N from B), row = quad*4 + reg (M)
    const size_t bm = (size_t)tm * GBM;
    const size_t bn = (size_t)tn * GBN;
    #pragma unroll
    for (int mi = 0; mi < 8; ++mi) {
        #pragma unroll
        for (int ni = 0; ni < 4; ++ni) {
            size_t col = bn + (size_t)waveN * 64 + ni * 16 + l16;
            #pragma unroll
            for (int r = 0; r < 4; ++r) {
                size_t row = bm + (size_t)waveM * 128 + mi * 16 + quad * 4 + r;
                C[row * N + col] = acc[mi][ni][r];
            }
        }
    }
}

// ---------------------------------------------------------------------------
extern "C" void kernel_launch(void* const* d_in, const int* in_sizes, int n_in,
                              void* d_out, int out_size, void* d_ws, size_t ws_size,
                              hipStream_t stream) {
    const float* x      = (const float*)d_in[0];
    const float* scale  = (const float*)d_in[1];
    const float* lnbias = (const float*)d_in[2];
    const float* W      = (const float*)d_in[3];

    const int H = in_sizes[1];                 // 2048
    const int M = in_sizes[0] / H;             // S*B = 8192
    const int F = in_sizes[3] / H;             // 8192

    float* z = (float*)d_out;                  // [M][F]
    float* y = z + (size_t)M * F;              // [M][H]

    unsigned short* Abf = (unsigned short*)d_ws;            // [M][H] bf16
    unsigned short* Btb = Abf + (size_t)M * H;              // [F][H] bf16

    ln_kernel<<<M, 256, 0, stream>>>(x, scale, lnbias, y, Abf, H);
    transpose_cast_kernel<<<dim3(F / 64, H / 64), 256, 0, stream>>>(W, Btb, H, F);
    gemm_bf16_8w<<<dim3((M / GBM) * (F / GBN)), 512, 0, stream>>>(Abf, Btb, z, M, F, H);
}